// Round 1
// baseline (2871.163 us; speedup 1.0000x reference)
//
#include <hip/hip_runtime.h>
#include <hip/hip_bf16.h>

// LSDAN: 3-hop masked graph attention, N=4096, IN_F=256, H=128.
// Strategy:
//  - masks of A^k computed as boolean bitset reachability (A is 0/1 + self loops,
//    walk counts are exact small ints in f32, so (A^k != 0) == k-hop reachability).
//  - e is rank-1: e[i][j] = lrelu(s1[i]+s2[j]); masked row-max via max s2 (monotone).
//  - masked softmax skips masked entries (exp(-1000 - max) == 0 in f32 exactly).
//  - per-row sparse compaction in LDS, gather-weighted sums in f32.

#define NN 4096
#define INF 256
#define HH 128
#define WPR 64          // 64-bit words per bitset row (4096/64)
#define ALPHA_S 0.2f

__device__ __forceinline__ float lrelu(float x) { return x > 0.f ? x : ALPHA_S * x; }

// ---- W1h = X @ W1_w.T, W2h = X @ W2_w.T (N x H each) ----
__global__ __launch_bounds__(256) void k_xw(const float* __restrict__ X,
                                            const float* __restrict__ W1,
                                            const float* __restrict__ W2,
                                            float* __restrict__ W1h,
                                            float* __restrict__ W2h) {
    __shared__ float xs[16 * INF];
    const int row0 = blockIdx.x * 16;
    const int t = threadIdx.x;
    for (int v = t; v < 16 * INF; v += 256) xs[v] = X[(size_t)row0 * INF + v];
    __syncthreads();
    const int c = t;  // 0..127 -> W1h col c ; 128..255 -> W2h col c-128
    const float* W = (c < HH) ? (W1 + (size_t)c * INF) : (W2 + (size_t)(c - HH) * INF);
    float acc[16];
#pragma unroll
    for (int r = 0; r < 16; ++r) acc[r] = 0.f;
    for (int k = 0; k < INF; ++k) {
        float wv = W[k];
#pragma unroll
        for (int r = 0; r < 16; ++r) acc[r] += xs[r * INF + k] * wv;
    }
    float* dst = (c < HH) ? W1h : W2h;
    const int cc = (c < HH) ? c : (c - HH);
    for (int r = 0; r < 16; ++r) dst[(size_t)(row0 + r) * HH + cc] = acc[r];
}

// ---- s1 = W1h @ r[:H], s2 = W1h @ r[H:] ----
__global__ void k_s(const float* __restrict__ W1h, const float* __restrict__ r,
                    float* __restrict__ s1, float* __restrict__ s2) {
    int i = blockIdx.x * blockDim.x + threadIdx.x;
    if (i >= NN) return;
    float a = 0.f, b = 0.f;
    for (int h = 0; h < HH; ++h) {
        float v = W1h[(size_t)i * HH + h];
        a += v * r[h];
        b += v * r[HH + h];
    }
    s1[i] = a;
    s2[i] = b;
}

// ---- B1[i] bitset from A row i ----
__global__ void k_b1(const float* __restrict__ A, unsigned long long* __restrict__ B1) {
    const int wave = threadIdx.x >> 6;
    const int lane = threadIdx.x & 63;
    const int i = blockIdx.x * 4 + wave;
    for (int w = 0; w < WPR; ++w) {
        float a = A[(size_t)i * NN + w * 64 + lane];
        unsigned long long m = __ballot(a != 0.0f);
        if (lane == 0) B1[(size_t)i * WPR + w] = m;
    }
}

// ---- boolean matmul: out row i = OR over set bits j of srcbits row i of mat row j ----
__global__ void k_boolmm(const unsigned long long* __restrict__ srcbits,
                         const unsigned long long* __restrict__ mat,
                         unsigned long long* __restrict__ out) {
    const int wave = threadIdx.x >> 6;
    const int lane = threadIdx.x & 63;
    const int i = blockIdx.x * 4 + wave;
    unsigned long long myword = srcbits[(size_t)i * WPR + lane];
    unsigned long long acc = 0ull;
    for (int w = 0; w < WPR; ++w) {
        unsigned long long bits = __shfl(myword, w, 64);
        while (bits) {
            int b = __builtin_ctzll(bits);
            bits &= bits - 1;
            int j = w * 64 + b;
            acc |= mat[(size_t)j * WPR + lane];
        }
    }
    out[(size_t)i * WPR + lane] = acc;
}

// ---- pass A: h_k[i] = softmax_row(masked e)[i] @ W1h ----
__global__ __launch_bounds__(256) void k_passA(const unsigned long long* __restrict__ Bk,
                                               const float* __restrict__ s1v,
                                               const float* __restrict__ s2v,
                                               const float* __restrict__ W1h,
                                               float* __restrict__ hbuf) {
    __shared__ unsigned long long bits[WPR];
    __shared__ int idxl[NN];
    __shared__ float wtl[NN];
    __shared__ float red[256];
    __shared__ int scn[256];
    __shared__ float hred[HH];
    const int i = blockIdx.x;
    const int t = threadIdx.x;
    if (t < WPR) bits[t] = Bk[(size_t)i * WPR + t];
    __syncthreads();
    // thread t owns columns [16t, 16t+16)
    unsigned long long wq = bits[t >> 2];
    unsigned int mybits = (unsigned int)((wq >> ((t & 3) * 16)) & 0xFFFFull);
    int cnt = __popc(mybits);
    scn[t] = cnt;
    __syncthreads();
    for (int off = 1; off < 256; off <<= 1) {
        int v = (t >= off) ? scn[t - off] : 0;
        __syncthreads();
        scn[t] += v;
        __syncthreads();
    }
    const int C = scn[255];
    int o = scn[t] - cnt;
    // compact (store s2 value for now), track max s2
    float mx = -1e30f;
    {
        unsigned int mb = mybits;
        while (mb) {
            int b = __builtin_ctz(mb);
            mb &= mb - 1;
            int j = t * 16 + b;
            float v = s2v[j];
            mx = fmaxf(mx, v);
            idxl[o] = j;
            wtl[o] = v;
            ++o;
        }
    }
    red[t] = mx;
    __syncthreads();
    for (int off = 128; off; off >>= 1) {
        if (t < off) red[t] = fmaxf(red[t], red[t + off]);
        __syncthreads();
    }
    const float s1i = s1v[i];
    const float M = lrelu(s1i + red[0]);  // monotone lrelu -> true masked row max
    __syncthreads();
    // weights + Z
    float z = 0.f;
    for (int e = t; e < C; e += 256) {
        float w = expf(lrelu(s1i + wtl[e]) - M);
        wtl[e] = w;
        z += w;
    }
    red[t] = z;
    __syncthreads();
    for (int off = 128; off; off >>= 1) {
        if (t < off) red[t] += red[t + off];
        __syncthreads();
    }
    const float invZ = 1.0f / red[0];
    // h accumulation: group g (0/1) handles entries e ≡ g (mod 2), dim = t & 127
    const int dim = t & 127;
    const int g = t >> 7;
    float acc = 0.f;
    for (int e = g; e < C; e += 2) acc += wtl[e] * W1h[(size_t)idxl[e] * HH + dim];
    if (g == 1) hred[dim] = acc;
    __syncthreads();
    if (g == 0) hbuf[(size_t)i * HH + dim] = (acc + hred[dim]) * invZ;
}

// ---- pass B: scores = mask(h @ W2h.T); out[i] += softmax_row(scores) @ h ----
__global__ __launch_bounds__(256) void k_passB(const unsigned long long* __restrict__ Bk,
                                               const float* __restrict__ hbuf,
                                               const float* __restrict__ W2h,
                                               float* __restrict__ accum, int first) {
    __shared__ unsigned long long bits[WPR];
    __shared__ int idxl[NN];
    __shared__ float scl[NN];
    __shared__ float hi[HH];
    __shared__ float red[256];
    __shared__ int scn[256];
    __shared__ float hred[HH];
    const int i = blockIdx.x;
    const int t = threadIdx.x;
    if (t < WPR) bits[t] = Bk[(size_t)i * WPR + t];
    if (t < HH) hi[t] = hbuf[(size_t)i * HH + t];
    __syncthreads();
    unsigned long long wq = bits[t >> 2];
    unsigned int mybits = (unsigned int)((wq >> ((t & 3) * 16)) & 0xFFFFull);
    int cnt = __popc(mybits);
    scn[t] = cnt;
    __syncthreads();
    for (int off = 1; off < 256; off <<= 1) {
        int v = (t >= off) ? scn[t - off] : 0;
        __syncthreads();
        scn[t] += v;
        __syncthreads();
    }
    const int C = scn[255];
    int o = scn[t] - cnt;
    {
        unsigned int mb = mybits;
        while (mb) {
            int b = __builtin_ctz(mb);
            mb &= mb - 1;
            idxl[o++] = t * 16 + b;
        }
    }
    __syncthreads();
    // scores
    float mx = -1e30f;
    for (int e = t; e < C; e += 256) {
        const float* wrow = W2h + (size_t)idxl[e] * HH;
        float s = 0.f;
#pragma unroll 8
        for (int k = 0; k < HH; ++k) s += hi[k] * wrow[k];
        scl[e] = s;
        mx = fmaxf(mx, s);
    }
    red[t] = mx;
    __syncthreads();
    for (int off = 128; off; off >>= 1) {
        if (t < off) red[t] = fmaxf(red[t], red[t + off]);
        __syncthreads();
    }
    const float M = red[0];
    __syncthreads();
    float z = 0.f;
    for (int e = t; e < C; e += 256) {
        float w = expf(scl[e] - M);
        scl[e] = w;
        z += w;
    }
    red[t] = z;
    __syncthreads();
    for (int off = 128; off; off >>= 1) {
        if (t < off) red[t] += red[t + off];
        __syncthreads();
    }
    const float invZ = 1.0f / red[0];
    const int dim = t & 127;
    const int g = t >> 7;
    float acc = 0.f;
    for (int e = g; e < C; e += 2) acc += scl[e] * hbuf[(size_t)idxl[e] * HH + dim];
    if (g == 1) hred[dim] = acc;
    __syncthreads();
    if (g == 0) {
        float v = (acc + hred[dim]) * invZ;
        float* dst = accum + (size_t)i * HH + dim;
        if (first) *dst = v;
        else *dst += v;
    }
}

// ---- finalize: out = [U_l + acc ; acc] ----
__global__ void k_fin(const float* __restrict__ Ul, const float* __restrict__ acc,
                      float* __restrict__ out) {
    int idx = blockIdx.x * 256 + threadIdx.x;
    float a = acc[idx];
    out[idx] = Ul[idx] + a;
    out[NN * HH + idx] = a;
}

extern "C" void kernel_launch(void* const* d_in, const int* in_sizes, int n_in,
                              void* d_out, int out_size, void* d_ws, size_t ws_size,
                              hipStream_t stream) {
    const float* X   = (const float*)d_in[0];
    const float* A   = (const float*)d_in[1];
    const float* Ul  = (const float*)d_in[2];
    const float* W1w = (const float*)d_in[3];
    const float* W2w = (const float*)d_in[4];
    const float* r   = (const float*)d_in[5];
    float* out = (float*)d_out;

    char* ws = (char*)d_ws;
    float* W1h = (float*)(ws + (0ull << 20));              // 2 MB
    float* W2h = (float*)(ws + (2ull << 20));              // 2 MB
    float* s1  = (float*)(ws + (4ull << 20));              // 16 KB
    float* s2  = (float*)(ws + (4ull << 20) + (64 << 10)); // 16 KB
    float* hbf = (float*)(ws + (5ull << 20));              // 2 MB
    float* acc = (float*)(ws + (7ull << 20));              // 2 MB
    unsigned long long* B1 = (unsigned long long*)(ws + (9ull << 20));   // 2 MB
    unsigned long long* B2 = (unsigned long long*)(ws + (11ull << 20));  // 2 MB
    unsigned long long* B3 = (unsigned long long*)(ws + (13ull << 20));  // 2 MB

    k_xw<<<NN / 16, 256, 0, stream>>>(X, W1w, W2w, W1h, W2h);
    k_s<<<NN / 256, 256, 0, stream>>>(W1h, r, s1, s2);
    k_b1<<<NN / 4, 256, 0, stream>>>(A, B1);
    k_boolmm<<<NN / 4, 256, 0, stream>>>(B1, B1, B2);  // structure of A^2
    k_boolmm<<<NN / 4, 256, 0, stream>>>(B1, B2, B3);  // structure of A^3 = A@(A@A)

    const unsigned long long* Bs[3] = {B1, B2, B3};
    for (int hop = 0; hop < 3; ++hop) {
        k_passA<<<NN, 256, 0, stream>>>(Bs[hop], s1, s2, W1h, hbf);
        k_passB<<<NN, 256, 0, stream>>>(Bs[hop], hbf, W2h, acc, hop == 0 ? 1 : 0);
    }
    k_fin<<<NN * HH / 256, 256, 0, stream>>>(Ul, acc, out);
}

// Round 2
// 510.843 us; speedup vs baseline: 5.6204x; 5.6204x over previous
//
#include <hip/hip_runtime.h>
#include <hip/hip_bf16.h>

// LSDAN: 3-hop masked graph attention, N=4096, IN_F=256, H=128.
//  - masks of A^k via boolean bitset reachability (A is 0/1 with self-loops).
//  - e is rank-1: e[i][j]=lrelu(s1[i]+s2[j]); masked row max via max s2 (monotone).
//  - masked entries contribute exp(-1000-M)==0 exactly in f32 -> skip them.
//  - per-hop: dense bf16 MFMA GEMMs on 16-row strips with masked softmax fused
//    in LDS (128KB strip, XOR-swizzled to kill ds_read_b128 bank conflicts).

#define NN 4096
#define INF 256
#define HH 128
#define WPR 64
#define ALPHA_S 0.2f

typedef short bf16x8 __attribute__((ext_vector_type(8)));
typedef float f32x4 __attribute__((ext_vector_type(4)));

__device__ __forceinline__ float lrelu(float x) { return x > 0.f ? x : ALPHA_S * x; }
__device__ __forceinline__ unsigned short f2bf(float x) {
    __hip_bfloat16 h = __float2bfloat16(x);
    return *reinterpret_cast<unsigned short*>(&h);
}
__device__ __forceinline__ float bf2f(unsigned short u) {
    unsigned int v = ((unsigned int)u) << 16;
    return __uint_as_float(v);
}

// ---- W1h = X@W1^T (f32 + bf16-transposed), W2h = X@W2^T (bf16 row-major) ----
__global__ __launch_bounds__(256) void k_xw(const float* __restrict__ X,
                                            const float* __restrict__ W1,
                                            const float* __restrict__ W2,
                                            float* __restrict__ W1h,
                                            unsigned short* __restrict__ W1hTb,
                                            unsigned short* __restrict__ W2hb) {
    __shared__ float xs[16 * INF];
    const int row0 = blockIdx.x * 16;
    const int t = threadIdx.x;
    for (int v = t; v < 16 * INF; v += 256) xs[v] = X[(size_t)row0 * INF + v];
    __syncthreads();
    const int c = t;
    const float* W = (c < HH) ? (W1 + (size_t)c * INF) : (W2 + (size_t)(c - HH) * INF);
    float acc[16];
#pragma unroll
    for (int r = 0; r < 16; ++r) acc[r] = 0.f;
    for (int k = 0; k < INF; ++k) {
        float wv = W[k];
#pragma unroll
        for (int r = 0; r < 16; ++r) acc[r] += xs[r * INF + k] * wv;
    }
    if (c < HH) {
        for (int r = 0; r < 16; ++r) {
            W1h[(size_t)(row0 + r) * HH + c] = acc[r];
            W1hTb[(size_t)c * NN + row0 + r] = f2bf(acc[r]);
        }
    } else {
        const int cc = c - HH;
        for (int r = 0; r < 16; ++r) W2hb[(size_t)(row0 + r) * HH + cc] = f2bf(acc[r]);
    }
}

// ---- s1 = W1h @ r[:H], s2 = W1h @ r[H:] ----
__global__ void k_s(const float* __restrict__ W1h, const float* __restrict__ r,
                    float* __restrict__ s1, float* __restrict__ s2) {
    int i = blockIdx.x * blockDim.x + threadIdx.x;
    if (i >= NN) return;
    float a = 0.f, b = 0.f;
    for (int h = 0; h < HH; ++h) {
        float v = W1h[(size_t)i * HH + h];
        a += v * r[h];
        b += v * r[HH + h];
    }
    s1[i] = a;
    s2[i] = b;
}

// ---- B1[i] bitset from A row i ----
__global__ void k_b1(const float* __restrict__ A, unsigned long long* __restrict__ B1) {
    const int wave = threadIdx.x >> 6;
    const int lane = threadIdx.x & 63;
    const int i = blockIdx.x * 4 + wave;
    for (int w = 0; w < WPR; ++w) {
        float a = A[(size_t)i * NN + w * 64 + lane];
        unsigned long long m = __ballot(a != 0.0f);
        if (lane == 0) B1[(size_t)i * WPR + w] = m;
    }
}

// ---- boolean matmul for reachability ----
__global__ void k_boolmm(const unsigned long long* __restrict__ srcbits,
                         const unsigned long long* __restrict__ mat,
                         unsigned long long* __restrict__ out) {
    const int wave = threadIdx.x >> 6;
    const int lane = threadIdx.x & 63;
    const int i = blockIdx.x * 4 + wave;
    unsigned long long myword = srcbits[(size_t)i * WPR + lane];
    unsigned long long acc = 0ull;
    for (int w = 0; w < WPR; ++w) {
        unsigned long long bits = __shfl(myword, w, 64);
        while (bits) {
            int b = __builtin_ctzll(bits);
            bits &= bits - 1;
            acc |= mat[(size_t)(w * 64 + b) * WPR + lane];
        }
    }
    out[(size_t)i * WPR + lane] = acc;
}

// ---- hop pass A: h strip = softmax_masked(rank1 e) @ W1h  (16 rows/block) ----
__global__ __launch_bounds__(512) void k_hopA(const unsigned long long* __restrict__ Bk,
                                              const float* __restrict__ s1v,
                                              const float* __restrict__ s2v,
                                              const unsigned short* __restrict__ W1hTb,
                                              unsigned short* __restrict__ h_rm,
                                              unsigned short* __restrict__ h_cm) {
    __shared__ unsigned short wl[16 * 4096] __attribute__((aligned(16)));  // 128KB weights
    __shared__ unsigned long long bits[16][WPR];                            // 8KB
    __shared__ float red[512];
    __shared__ float Mr[16], Zi[16], s1l[16];
    const int i0 = blockIdx.x * 16;
    const int t = threadIdx.x;
    for (int v = t; v < 16 * WPR; v += 512)
        bits[v >> 6][v & 63] = Bk[(size_t)(i0 + (v >> 6)) * WPR + (v & 63)];
    if (t < 16) s1l[t] = s1v[i0 + t];
    __syncthreads();
    const int r = t >> 5, lig = t & 31;
    // masked row max of s2
    float mx = -1e30f;
    for (int jj = 0; jj < 128; ++jj) {
        int j = lig + (jj << 5);
        if ((bits[r][j >> 6] >> (j & 63)) & 1ull) mx = fmaxf(mx, s2v[j]);
    }
    red[t] = mx;
    __syncthreads();
    for (int off = 16; off; off >>= 1) {
        if ((t & 31) < off) red[t] = fmaxf(red[t], red[t + off]);
        __syncthreads();
    }
    if ((t & 31) == 0) Mr[r] = lrelu(s1l[r] + red[t]);
    __syncthreads();
    // fill dense bf16 weight strip (swizzled) + Z
    const float s1r = s1l[r], M = Mr[r];
    float z = 0.f;
    for (int jj = 0; jj < 128; ++jj) {
        int j = lig + (jj << 5);
        unsigned short val = 0;
        if ((bits[r][j >> 6] >> (j & 63)) & 1ull) {
            float e = __expf(lrelu(s1r + s2v[j]) - M);
            z += e;
            val = f2bf(e);
        }
        wl[(r * 4096 + j) ^ ((r & 7) << 3)] = val;
    }
    red[t] = z;
    __syncthreads();
    for (int off = 16; off; off >>= 1) {
        if ((t & 31) < off) red[t] += red[t + off];
        __syncthreads();
    }
    if ((t & 31) == 0) Zi[r] = 1.0f / red[t];
    __syncthreads();
    // GEMM: h strip = wl @ W1h ; wave per 16-col tile, K=4096
    const int wv = t >> 6, lane = t & 63;
    const int col = (wv << 4) + (lane & 15);
    const int kg = lane >> 4;
    const int arow = lane & 15;
    const int abase = arow * 4096 + kg * 8;
    const int asw = (arow & 7) << 3;
    f32x4 acc = {0.f, 0.f, 0.f, 0.f};
#pragma unroll 4
    for (int k0 = 0; k0 < 4096; k0 += 32) {
        bf16x8 a = *reinterpret_cast<const bf16x8*>(&wl[(abase + k0) ^ asw]);
        bf16x8 b = *reinterpret_cast<const bf16x8*>(&W1hTb[(size_t)col * NN + kg * 8 + k0]);
        acc = __builtin_amdgcn_mfma_f32_16x16x32_bf16(a, b, acc, 0, 0, 0);
    }
#pragma unroll
    for (int ri = 0; ri < 4; ++ri) {
        int row = kg * 4 + ri;
        unsigned short hv = f2bf(acc[ri] * Zi[row]);
        h_rm[(size_t)(i0 + row) * HH + col] = hv;
        h_cm[(size_t)col * NN + i0 + row] = hv;
    }
}

// ---- hop pass B: S=h@W2h^T, masked softmax, out += w @ h  (16 rows/block) ----
__global__ __launch_bounds__(512) void k_hopB(const unsigned long long* __restrict__ Bk,
                                              const unsigned short* __restrict__ h_rm,
                                              const unsigned short* __restrict__ W2hb,
                                              const unsigned short* __restrict__ h_cm,
                                              float* __restrict__ accb, int first) {
    __shared__ unsigned short sl[16 * 4096] __attribute__((aligned(16)));  // 128KB S/weights
    __shared__ unsigned long long bits[16][WPR];
    __shared__ float red[512];
    __shared__ float Mr[16], Zi[16];
    const int i0 = blockIdx.x * 16;
    const int t = threadIdx.x;
    for (int v = t; v < 16 * WPR; v += 512)
        bits[v >> 6][v & 63] = Bk[(size_t)(i0 + (v >> 6)) * WPR + (v & 63)];
    const int wv = t >> 6, lane = t & 63;
    const int kg = lane >> 4;
    const int arow = lane & 15;
    // A fragments: h strip rows (K=128 -> 4 frags), from global bf16
    bf16x8 af[4];
#pragma unroll
    for (int ks = 0; ks < 4; ++ks)
        af[ks] = *reinterpret_cast<const bf16x8*>(&h_rm[(size_t)(i0 + arow) * HH + ks * 32 + kg * 8]);
    // S sweep: each wave does 32 16x16 tiles across the 4096 cols
    for (int m = 0; m < 32; ++m) {
        const int col = ((wv + (m << 3)) << 4) + (lane & 15);
        f32x4 acc = {0.f, 0.f, 0.f, 0.f};
#pragma unroll
        for (int ks = 0; ks < 4; ++ks) {
            bf16x8 b = *reinterpret_cast<const bf16x8*>(&W2hb[(size_t)col * HH + ks * 32 + kg * 8]);
            acc = __builtin_amdgcn_mfma_f32_16x16x32_bf16(af[ks], b, acc, 0, 0, 0);
        }
#pragma unroll
        for (int ri = 0; ri < 4; ++ri) {
            int row = kg * 4 + ri;
            sl[(row * 4096 + col) ^ ((row & 7) << 3)] = f2bf(acc[ri]);
        }
    }
    __syncthreads();
    // masked softmax over sl
    const int r = t >> 5, lig = t & 31;
    float mx = -1e30f;
    for (int jj = 0; jj < 128; ++jj) {
        int j = lig + (jj << 5);
        if ((bits[r][j >> 6] >> (j & 63)) & 1ull)
            mx = fmaxf(mx, bf2f(sl[(r * 4096 + j) ^ ((r & 7) << 3)]));
    }
    red[t] = mx;
    __syncthreads();
    for (int off = 16; off; off >>= 1) {
        if ((t & 31) < off) red[t] = fmaxf(red[t], red[t + off]);
        __syncthreads();
    }
    if ((t & 31) == 0) Mr[r] = red[t];
    __syncthreads();
    const float M = Mr[r];
    float z = 0.f;
    for (int jj = 0; jj < 128; ++jj) {
        int j = lig + (jj << 5);
        int idx = (r * 4096 + j) ^ ((r & 7) << 3);
        unsigned short v = 0;
        if ((bits[r][j >> 6] >> (j & 63)) & 1ull) {
            float e = __expf(bf2f(sl[idx]) - M);
            z += e;
            v = f2bf(e);
        }
        sl[idx] = v;
    }
    red[t] = z;
    __syncthreads();
    for (int off = 16; off; off >>= 1) {
        if ((t & 31) < off) red[t] += red[t + off];
        __syncthreads();
    }
    if ((t & 31) == 0) Zi[r] = 1.0f / red[t];
    __syncthreads();
    // GEMM2: out strip += (sl * invZ) @ h ; B from h_cm (transposed h), K=4096
    const int col = (wv << 4) + (lane & 15);
    const int abase = arow * 4096 + kg * 8;
    const int asw = (arow & 7) << 3;
    f32x4 acc = {0.f, 0.f, 0.f, 0.f};
#pragma unroll 4
    for (int k0 = 0; k0 < 4096; k0 += 32) {
        bf16x8 a = *reinterpret_cast<const bf16x8*>(&sl[(abase + k0) ^ asw]);
        bf16x8 b = *reinterpret_cast<const bf16x8*>(&h_cm[(size_t)col * NN + kg * 8 + k0]);
        acc = __builtin_amdgcn_mfma_f32_16x16x32_bf16(a, b, acc, 0, 0, 0);
    }
#pragma unroll
    for (int ri = 0; ri < 4; ++ri) {
        int row = kg * 4 + ri;
        float v = acc[ri] * Zi[row];
        float* dst = accb + (size_t)(i0 + row) * HH + col;
        if (first) *dst = v;
        else *dst += v;
    }
}

// ---- finalize: out = [U_l + acc ; acc] ----
__global__ void k_fin(const float* __restrict__ Ul, const float* __restrict__ acc,
                      float* __restrict__ out) {
    int idx = blockIdx.x * 256 + threadIdx.x;
    float a = acc[idx];
    out[idx] = Ul[idx] + a;
    out[NN * HH + idx] = a;
}

extern "C" void kernel_launch(void* const* d_in, const int* in_sizes, int n_in,
                              void* d_out, int out_size, void* d_ws, size_t ws_size,
                              hipStream_t stream) {
    const float* X   = (const float*)d_in[0];
    const float* A   = (const float*)d_in[1];
    const float* Ul  = (const float*)d_in[2];
    const float* W1w = (const float*)d_in[3];
    const float* W2w = (const float*)d_in[4];
    const float* r   = (const float*)d_in[5];
    float* out = (float*)d_out;

    char* ws = (char*)d_ws;
    float* W1h            = (float*)(ws + (0ull << 20));               // 2 MB f32
    float* s1             = (float*)(ws + (4ull << 20));               // 16 KB
    float* s2             = (float*)(ws + (4ull << 20) + (64 << 10));  // 16 KB
    unsigned short* W1hTb = (unsigned short*)(ws + (5ull << 20));      // 1 MB bf16 (128x4096)
    unsigned short* W2hb  = (unsigned short*)(ws + (6ull << 20));      // 1 MB bf16 (4096x128)
    unsigned short* h_rm  = (unsigned short*)(ws + (7ull << 20));      // 1 MB bf16 (4096x128)
    unsigned short* h_cm  = (unsigned short*)(ws + (8ull << 20));      // 1 MB bf16 (128x4096)
    float* accb           = (float*)(ws + (9ull << 20));               // 2 MB f32
    unsigned long long* B1 = (unsigned long long*)(ws + (11ull << 20));
    unsigned long long* B2 = (unsigned long long*)(ws + (13ull << 20));
    unsigned long long* B3 = (unsigned long long*)(ws + (15ull << 20));

    k_xw<<<NN / 16, 256, 0, stream>>>(X, W1w, W2w, W1h, W1hTb, W2hb);
    k_s<<<NN / 256, 256, 0, stream>>>(W1h, r, s1, s2);
    k_b1<<<NN / 4, 256, 0, stream>>>(A, B1);
    k_boolmm<<<NN / 4, 256, 0, stream>>>(B1, B1, B2);
    k_boolmm<<<NN / 4, 256, 0, stream>>>(B1, B2, B3);

    const unsigned long long* Bs[3] = {B1, B2, B3};
    for (int hop = 0; hop < 3; ++hop) {
        k_hopA<<<NN / 16, 512, 0, stream>>>(Bs[hop], s1, s2, W1hTb, h_rm, h_cm);
        k_hopB<<<NN / 16, 512, 0, stream>>>(Bs[hop], h_rm, W2hb, h_cm, accb, hop == 0 ? 1 : 0);
    }
    k_fin<<<NN * HH / 256, 256, 0, stream>>>(Ul, accb, out);
}

// Round 3
// 398.121 us; speedup vs baseline: 7.2118x; 1.2831x over previous
//
#include <hip/hip_runtime.h>
#include <hip/hip_bf16.h>

// LSDAN: 3-hop masked graph attention, N=4096, IN_F=256, H=128.
//  - masks of A^k via boolean bitset reachability (A is 0/1 with self-loops).
//  - e is rank-1: e[i][j]=lrelu(s1[i]+s2[j]); softmax shift M = lrelu(s1+gmax(s2))
//    (upper bound, monotone lrelu; exp args in [-6,0] -> no flush issues).
//  - hopB row max tracked in registers during the S MFMA sweep (unmasked >= masked).
//  - softmax phases fully vectorized: b128 LDS ops, branchless byte-mask selects.
//  - 1024 thr/block (16 waves/CU), wave-per-row softmax, split-K MFMA GEMMs.

#define NN 4096
#define INF 256
#define HH 128
#define WPR 64
#define ALPHA_S 0.2f

typedef short bf16x8 __attribute__((ext_vector_type(8)));
typedef float f32x4 __attribute__((ext_vector_type(4)));

__device__ __forceinline__ float lrelu(float x) { return x > 0.f ? x : ALPHA_S * x; }
__device__ __forceinline__ unsigned short f2bf(float x) {
    __hip_bfloat16 h = __float2bfloat16(x);
    return *reinterpret_cast<unsigned short*>(&h);
}
__device__ __forceinline__ float bf2f(unsigned short u) {
    return __uint_as_float(((unsigned int)u) << 16);
}

// ---- W1h = X@W1^T (f32 + bf16-transposed), W2h = X@W2^T (bf16 row-major) ----
__global__ __launch_bounds__(256) void k_xw(const float* __restrict__ X,
                                            const float* __restrict__ W1,
                                            const float* __restrict__ W2,
                                            float* __restrict__ W1h,
                                            unsigned short* __restrict__ W1hTb,
                                            unsigned short* __restrict__ W2hb) {
    __shared__ float xs[16 * INF];
    const int row0 = blockIdx.x * 16;
    const int t = threadIdx.x;
    for (int v = t; v < 16 * INF; v += 256) xs[v] = X[(size_t)row0 * INF + v];
    __syncthreads();
    const int c = t;
    const float* W = (c < HH) ? (W1 + (size_t)c * INF) : (W2 + (size_t)(c - HH) * INF);
    float acc[16];
#pragma unroll
    for (int r = 0; r < 16; ++r) acc[r] = 0.f;
    for (int k = 0; k < INF; ++k) {
        float wv = W[k];
#pragma unroll
        for (int r = 0; r < 16; ++r) acc[r] += xs[r * INF + k] * wv;
    }
    if (c < HH) {
        for (int r = 0; r < 16; ++r) {
            W1h[(size_t)(row0 + r) * HH + c] = acc[r];
            W1hTb[(size_t)c * NN + row0 + r] = f2bf(acc[r]);
        }
    } else {
        const int cc = c - HH;
        for (int r = 0; r < 16; ++r) W2hb[(size_t)(row0 + r) * HH + cc] = f2bf(acc[r]);
    }
}

// ---- s1 = W1h @ r[:H], s2 = W1h @ r[H:] ----
__global__ void k_s(const float* __restrict__ W1h, const float* __restrict__ r,
                    float* __restrict__ s1, float* __restrict__ s2) {
    int i = blockIdx.x * blockDim.x + threadIdx.x;
    if (i >= NN) return;
    float a = 0.f, b = 0.f;
    for (int h = 0; h < HH; ++h) {
        float v = W1h[(size_t)i * HH + h];
        a += v * r[h];
        b += v * r[HH + h];
    }
    s1[i] = a;
    s2[i] = b;
}

// ---- global max of s2 ----
__global__ void k_gmax(const float* __restrict__ s2, float* __restrict__ out) {
    __shared__ float red[256];
    const int t = threadIdx.x;
    float m = -1e30f;
    for (int i = t; i < NN; i += 256) m = fmaxf(m, s2[i]);
    red[t] = m;
    __syncthreads();
    for (int off = 128; off; off >>= 1) {
        if (t < off) red[t] = fmaxf(red[t], red[t + off]);
        __syncthreads();
    }
    if (t == 0) out[0] = red[0];
}

// ---- B1[i] bitset from A row i ----
__global__ void k_b1(const float* __restrict__ A, unsigned long long* __restrict__ B1) {
    const int wave = threadIdx.x >> 6;
    const int lane = threadIdx.x & 63;
    const int i = blockIdx.x * 4 + wave;
    for (int w = 0; w < WPR; ++w) {
        float a = A[(size_t)i * NN + w * 64 + lane];
        unsigned long long m = __ballot(a != 0.0f);
        if (lane == 0) B1[(size_t)i * WPR + w] = m;
    }
}

// ---- boolean matmul for reachability ----
__global__ void k_boolmm(const unsigned long long* __restrict__ srcbits,
                         const unsigned long long* __restrict__ mat,
                         unsigned long long* __restrict__ out) {
    const int wave = threadIdx.x >> 6;
    const int lane = threadIdx.x & 63;
    const int i = blockIdx.x * 4 + wave;
    unsigned long long myword = srcbits[(size_t)i * WPR + lane];
    unsigned long long acc = 0ull;
    for (int w = 0; w < WPR; ++w) {
        unsigned long long bits = __shfl(myword, w, 64);
        while (bits) {
            int b = __builtin_ctzll(bits);
            bits &= bits - 1;
            acc |= mat[(size_t)(w * 64 + b) * WPR + lane];
        }
    }
    out[(size_t)i * WPR + lane] = acc;
}

// ---- hop pass A: h strip = softmax_masked(rank1 e) @ W1h  (16 rows/block) ----
__global__ __launch_bounds__(1024) void k_hopA(const unsigned long long* __restrict__ Bk,
                                               const float* __restrict__ s1v,
                                               const float* __restrict__ s2v,
                                               const float* __restrict__ s2mx,
                                               const unsigned short* __restrict__ W1hTb,
                                               unsigned short* __restrict__ h_rm,
                                               unsigned short* __restrict__ h_cm) {
    __shared__ unsigned short wl[16 * 4096] __attribute__((aligned(16)));  // 128 KB
    __shared__ unsigned long long bits[16][WPR];                            // 8 KB
    __shared__ f32x4 pacc[8][64];                                           // 8 KB
    __shared__ float Zi[16];
    const int i0 = blockIdx.x * 16;
    const int t = threadIdx.x;
    const int wv = t >> 6, lane = t & 63;
    for (int v = t; v < 16 * WPR; v += 1024)
        bits[v >> 6][v & 63] = Bk[(size_t)(i0 + (v >> 6)) * WPR + (v & 63)];
    __syncthreads();
    // fill: wave wv owns row wv. Branchless, vectorized, byte-mask.
    {
        const int r = wv;
        const float s1r = s1v[i0 + r];
        const float M = lrelu(s1r + s2mx[0]);
        const int swz = (r & 7) << 3;
        float z = 0.f;
#pragma unroll
        for (int jj = 0; jj < 8; ++jj) {
            const int j0 = lane * 8 + jj * 512;
            const unsigned int mb = (unsigned int)(bits[r][j0 >> 6] >> (j0 & 63)) & 0xFFu;
            const float4 va = *reinterpret_cast<const float4*>(&s2v[j0]);
            const float4 vb = *reinterpret_cast<const float4*>(&s2v[j0 + 4]);
            float sv[8] = {va.x, va.y, va.z, va.w, vb.x, vb.y, vb.z, vb.w};
            bf16x8 pk;
#pragma unroll
            for (int b = 0; b < 8; ++b) {
                float f = ((mb >> b) & 1u) ? __expf(lrelu(s1r + sv[b]) - M) : 0.f;
                z += f;
                pk[b] = (short)f2bf(f);
            }
            *reinterpret_cast<bf16x8*>(&wl[(r * 4096 + j0) ^ swz]) = pk;
        }
#pragma unroll
        for (int m = 1; m < 64; m <<= 1) z += __shfl_xor(z, m, 64);
        if (lane == 0) Zi[r] = 1.f / z;
    }
    __syncthreads();
    // GEMM split-K: h strip = wl @ W1h. kh = K-half, 8 col-waves x 2 K-halves.
    const int kh = wv >> 3;
    const int col = ((wv & 7) << 4) + (lane & 15);
    const int kg = lane >> 4;
    const int arow = lane & 15;
    const int asw = (arow & 7) << 3;
    const int kbase = kh * 2048;
    f32x4 acc = {0.f, 0.f, 0.f, 0.f};
    const unsigned short* bp = W1hTb + (size_t)col * NN + kg * 8 + kbase;
    const int abase = arow * 4096 + kg * 8 + kbase;
#pragma unroll 4
    for (int k0 = 0; k0 < 2048; k0 += 32) {
        bf16x8 a = *reinterpret_cast<const bf16x8*>(&wl[(abase + k0) ^ asw]);
        bf16x8 b = *reinterpret_cast<const bf16x8*>(&bp[k0]);
        acc = __builtin_amdgcn_mfma_f32_16x16x32_bf16(a, b, acc, 0, 0, 0);
    }
    if (kh == 1) pacc[wv & 7][lane] = acc;
    __syncthreads();
    if (kh == 0) {
        f32x4 p = pacc[wv][lane];
#pragma unroll
        for (int ri = 0; ri < 4; ++ri) {
            const int row = kg * 4 + ri;
            const unsigned short hv = f2bf((acc[ri] + p[ri]) * Zi[row]);
            h_rm[(size_t)(i0 + row) * HH + col] = hv;
            h_cm[(size_t)col * NN + i0 + row] = hv;
        }
    }
}

// ---- hop pass B: S=h@W2h^T (max in regs), masked softmax, out += w @ h ----
__global__ __launch_bounds__(1024) void k_hopB(const unsigned long long* __restrict__ Bk,
                                               const unsigned short* __restrict__ h_rm,
                                               const unsigned short* __restrict__ W2hb,
                                               const unsigned short* __restrict__ h_cm,
                                               float* __restrict__ accb, int first) {
    __shared__ unsigned short sl[16 * 4096] __attribute__((aligned(16)));  // 128 KB
    __shared__ unsigned long long bits[16][WPR];                            // 8 KB
    __shared__ f32x4 pacc[8][64];                                           // 8 KB
    __shared__ float redM[16][16];                                          // 1 KB
    __shared__ float Zi[16];
    const int i0 = blockIdx.x * 16;
    const int t = threadIdx.x;
    const int wv = t >> 6, lane = t & 63;
    const int kg = lane >> 4, arow = lane & 15;
    for (int v = t; v < 16 * WPR; v += 1024)
        bits[v >> 6][v & 63] = Bk[(size_t)(i0 + (v >> 6)) * WPR + (v & 63)];
    // A fragments: strip rows of h (K=128 -> 4 frags)
    bf16x8 af[4];
#pragma unroll
    for (int ks = 0; ks < 4; ++ks)
        af[ks] = *reinterpret_cast<const bf16x8*>(&h_rm[(size_t)(i0 + arow) * HH + ks * 32 + kg * 8]);
    // S sweep: 16 waves x 16 col-tiles; track row max in registers.
    float vmax[4] = {-1e30f, -1e30f, -1e30f, -1e30f};
    for (int m = 0; m < 16; ++m) {
        const int col = ((wv * 16 + m) << 4) + (lane & 15);
        f32x4 acc = {0.f, 0.f, 0.f, 0.f};
#pragma unroll
        for (int ks = 0; ks < 4; ++ks) {
            bf16x8 b = *reinterpret_cast<const bf16x8*>(&W2hb[(size_t)col * HH + ks * 32 + kg * 8]);
            acc = __builtin_amdgcn_mfma_f32_16x16x32_bf16(af[ks], b, acc, 0, 0, 0);
        }
#pragma unroll
        for (int ri = 0; ri < 4; ++ri) {
            const int row = kg * 4 + ri;
            sl[(row * 4096 + col) ^ ((row & 7) << 3)] = f2bf(acc[ri]);
            vmax[ri] = fmaxf(vmax[ri], acc[ri]);
        }
    }
#pragma unroll
    for (int ri = 0; ri < 4; ++ri) {
        vmax[ri] = fmaxf(vmax[ri], __shfl_xor(vmax[ri], 1, 64));
        vmax[ri] = fmaxf(vmax[ri], __shfl_xor(vmax[ri], 2, 64));
        vmax[ri] = fmaxf(vmax[ri], __shfl_xor(vmax[ri], 4, 64));
        vmax[ri] = fmaxf(vmax[ri], __shfl_xor(vmax[ri], 8, 64));
    }
    if ((lane & 15) == 0) {
#pragma unroll
        for (int ri = 0; ri < 4; ++ri) redM[wv][kg * 4 + ri] = vmax[ri];
    }
    __syncthreads();
    // masked exp + Z: wave wv owns row wv (vectorized, branchless)
    {
        const int r = wv;
        float M = -1e30f;
#pragma unroll
        for (int w = 0; w < 16; ++w) M = fmaxf(M, redM[w][r]);
        const int swz = (r & 7) << 3;
        float z = 0.f;
#pragma unroll
        for (int jj = 0; jj < 8; ++jj) {
            const int j0 = lane * 8 + jj * 512;
            const unsigned int mb = (unsigned int)(bits[r][j0 >> 6] >> (j0 & 63)) & 0xFFu;
            unsigned short* p = &sl[(r * 4096 + j0) ^ swz];
            bf16x8 v = *reinterpret_cast<bf16x8*>(p);
            bf16x8 o;
#pragma unroll
            for (int b = 0; b < 8; ++b) {
                float f = ((mb >> b) & 1u) ? __expf(bf2f((unsigned short)v[b]) - M) : 0.f;
                z += f;
                o[b] = (short)f2bf(f);
            }
            *reinterpret_cast<bf16x8*>(p) = o;
        }
#pragma unroll
        for (int m = 1; m < 64; m <<= 1) z += __shfl_xor(z, m, 64);
        if (lane == 0) Zi[r] = 1.f / z;
    }
    __syncthreads();
    // GEMM2 split-K: out strip += (sl/Z) @ h
    const int kh = wv >> 3;
    const int col = ((wv & 7) << 4) + (lane & 15);
    const int asw = (arow & 7) << 3;
    const int kbase = kh * 2048;
    f32x4 acc = {0.f, 0.f, 0.f, 0.f};
    const unsigned short* bp = h_cm + (size_t)col * NN + kg * 8 + kbase;
    const int abase = arow * 4096 + kg * 8 + kbase;
#pragma unroll 4
    for (int k0 = 0; k0 < 2048; k0 += 32) {
        bf16x8 a = *reinterpret_cast<const bf16x8*>(&sl[(abase + k0) ^ asw]);
        bf16x8 b = *reinterpret_cast<const bf16x8*>(&bp[k0]);
        acc = __builtin_amdgcn_mfma_f32_16x16x32_bf16(a, b, acc, 0, 0, 0);
    }
    if (kh == 1) pacc[wv & 7][lane] = acc;
    __syncthreads();
    if (kh == 0) {
        f32x4 p = pacc[wv][lane];
#pragma unroll
        for (int ri = 0; ri < 4; ++ri) {
            const int row = kg * 4 + ri;
            float v = (acc[ri] + p[ri]) * Zi[row];
            float* dst = accb + (size_t)(i0 + row) * HH + col;
            if (first) *dst = v;
            else *dst += v;
        }
    }
}

// ---- finalize: out = [U_l + acc ; acc] ----
__global__ void k_fin(const float* __restrict__ Ul, const float* __restrict__ acc,
                      float* __restrict__ out) {
    int idx = blockIdx.x * 256 + threadIdx.x;
    float a = acc[idx];
    out[idx] = Ul[idx] + a;
    out[NN * HH + idx] = a;
}

extern "C" void kernel_launch(void* const* d_in, const int* in_sizes, int n_in,
                              void* d_out, int out_size, void* d_ws, size_t ws_size,
                              hipStream_t stream) {
    const float* X   = (const float*)d_in[0];
    const float* A   = (const float*)d_in[1];
    const float* Ul  = (const float*)d_in[2];
    const float* W1w = (const float*)d_in[3];
    const float* W2w = (const float*)d_in[4];
    const float* r   = (const float*)d_in[5];
    float* out = (float*)d_out;

    char* ws = (char*)d_ws;
    float* W1h            = (float*)(ws + (0ull << 20));               // 2 MB f32
    float* s1             = (float*)(ws + (4ull << 20));               // 16 KB
    float* s2             = (float*)(ws + (4ull << 20) + (64 << 10));  // 16 KB
    float* s2mx           = (float*)(ws + (4ull << 20) + (128 << 10)); // 4 B
    unsigned short* W1hTb = (unsigned short*)(ws + (5ull << 20));      // 1 MB bf16 (128x4096)
    unsigned short* W2hb  = (unsigned short*)(ws + (6ull << 20));      // 1 MB bf16 (4096x128)
    unsigned short* h_rm  = (unsigned short*)(ws + (7ull << 20));      // 1 MB bf16 (4096x128)
    unsigned short* h_cm  = (unsigned short*)(ws + (8ull << 20));      // 1 MB bf16 (128x4096)
    float* accb           = (float*)(ws + (9ull << 20));               // 2 MB f32
    unsigned long long* B1 = (unsigned long long*)(ws + (11ull << 20));
    unsigned long long* B2 = (unsigned long long*)(ws + (13ull << 20));
    unsigned long long* B3 = (unsigned long long*)(ws + (15ull << 20));

    k_xw<<<NN / 16, 256, 0, stream>>>(X, W1w, W2w, W1h, W1hTb, W2hb);
    k_s<<<NN / 256, 256, 0, stream>>>(W1h, r, s1, s2);
    k_gmax<<<1, 256, 0, stream>>>(s2, s2mx);
    k_b1<<<NN / 4, 256, 0, stream>>>(A, B1);
    k_boolmm<<<NN / 4, 256, 0, stream>>>(B1, B1, B2);
    k_boolmm<<<NN / 4, 256, 0, stream>>>(B1, B2, B3);

    const unsigned long long* Bs[3] = {B1, B2, B3};
    for (int hop = 0; hop < 3; ++hop) {
        k_hopA<<<NN / 16, 1024, 0, stream>>>(Bs[hop], s1, s2, s2mx, W1hTb, h_rm, h_cm);
        k_hopB<<<NN / 16, 1024, 0, stream>>>(Bs[hop], h_rm, W2hb, h_cm, accb, hop == 0 ? 1 : 0);
    }
    k_fin<<<NN * HH / 256, 256, 0, stream>>>(Ul, accb, out);
}

// Round 4
// 388.189 us; speedup vs baseline: 7.3963x; 1.0256x over previous
//
#include <hip/hip_runtime.h>
#include <hip/hip_bf16.h>

// LSDAN: 3-hop masked graph attention, N=4096, IN_F=256, H=128.
//  - masks of A^k via boolean bitset reachability (A is 0/1 with self-loops).
//  - e is rank-1: e[i][j]=lrelu(s1[i]+s2[j]); shift M = lrelu(s1+gmax(s2)) (upper bound).
//  - hopB row max tracked in registers during the S MFMA sweep (unmasked >= masked).
//  - softmax weights stored in MFMA-A-FRAGMENT granule order in LDS:
//      granule(c,l') holds S[l'&15][c*32 + (l'>>4)*8 .. +8], at u16 idx ((c<<6)|(l'^(c&7)))<<3.
//    -> GEMM A-reads are contiguous-permuted 1KB/instr (conflict-free); exp-phase
//       granule writes hit 8 distinct 128B windows per bank class (full BW).
//  - mask bits held in per-wave registers, broadcast via __shfl (no LDS bits).
//  - all 3 hops merged per pass (768 blocks); per-hop acc buffers summed in k_fin.

#define NN 4096
#define INF 256
#define HH 128
#define WPR 64
#define ALPHA_S 0.2f

typedef short bf16x8 __attribute__((ext_vector_type(8)));
typedef float f32x4 __attribute__((ext_vector_type(4)));

__device__ __forceinline__ float lrelu(float x) { return x > 0.f ? x : ALPHA_S * x; }
__device__ __forceinline__ unsigned short f2bf(float x) {
    __hip_bfloat16 h = __float2bfloat16(x);
    return *reinterpret_cast<unsigned short*>(&h);
}
__device__ __forceinline__ float bf2f(unsigned short u) {
    return __uint_as_float(((unsigned int)u) << 16);
}
// u16 index of a 16B A-fragment granule: chunk c (K/32), lane-id l' = (kg<<4)|arow
__device__ __forceinline__ int agran(int c, int lp) {
    return ((c << 6) | (lp ^ (c & 7))) << 3;
}

// ---- W1h = X@W1^T (f32 + bf16-transposed), W2h = X@W2^T (bf16 row-major) ----
__global__ __launch_bounds__(256) void k_xw(const float* __restrict__ X,
                                            const float* __restrict__ W1,
                                            const float* __restrict__ W2,
                                            float* __restrict__ W1h,
                                            unsigned short* __restrict__ W1hTb,
                                            unsigned short* __restrict__ W2hb) {
    __shared__ float xs[16 * INF];
    const int row0 = blockIdx.x * 16;
    const int t = threadIdx.x;
    for (int v = t; v < 16 * INF; v += 256) xs[v] = X[(size_t)row0 * INF + v];
    __syncthreads();
    const int c = t;
    const float* W = (c < HH) ? (W1 + (size_t)c * INF) : (W2 + (size_t)(c - HH) * INF);
    float acc[16];
#pragma unroll
    for (int r = 0; r < 16; ++r) acc[r] = 0.f;
    for (int k = 0; k < INF; ++k) {
        float wv = W[k];
#pragma unroll
        for (int r = 0; r < 16; ++r) acc[r] += xs[r * INF + k] * wv;
    }
    if (c < HH) {
        for (int r = 0; r < 16; ++r) {
            W1h[(size_t)(row0 + r) * HH + c] = acc[r];
            W1hTb[(size_t)c * NN + row0 + r] = f2bf(acc[r]);
        }
    } else {
        const int cc = c - HH;
        for (int r = 0; r < 16; ++r) W2hb[(size_t)(row0 + r) * HH + cc] = f2bf(acc[r]);
    }
}

// ---- s1 = W1h @ r[:H], s2 = W1h @ r[H:] ----
__global__ void k_s(const float* __restrict__ W1h, const float* __restrict__ r,
                    float* __restrict__ s1, float* __restrict__ s2) {
    int i = blockIdx.x * blockDim.x + threadIdx.x;
    if (i >= NN) return;
    float a = 0.f, b = 0.f;
    for (int h = 0; h < HH; ++h) {
        float v = W1h[(size_t)i * HH + h];
        a += v * r[h];
        b += v * r[HH + h];
    }
    s1[i] = a;
    s2[i] = b;
}

// ---- global max of s2 ----
__global__ void k_gmax(const float* __restrict__ s2, float* __restrict__ out) {
    __shared__ float red[256];
    const int t = threadIdx.x;
    float m = -3e38f;
    for (int i = t; i < NN; i += 256) m = fmaxf(m, s2[i]);
    red[t] = m;
    __syncthreads();
    for (int off = 128; off; off >>= 1) {
        if (t < off) red[t] = fmaxf(red[t], red[t + off]);
        __syncthreads();
    }
    if (t == 0) out[0] = red[0];
}

// ---- B1[i] bitset from A row i ----
__global__ void k_b1(const float* __restrict__ A, unsigned long long* __restrict__ B1) {
    const int wave = threadIdx.x >> 6;
    const int lane = threadIdx.x & 63;
    const int i = blockIdx.x * 4 + wave;
    for (int w = 0; w < WPR; ++w) {
        float a = A[(size_t)i * NN + w * 64 + lane];
        unsigned long long m = __ballot(a != 0.0f);
        if (lane == 0) B1[(size_t)i * WPR + w] = m;
    }
}

// ---- boolean matmul for reachability ----
__global__ void k_boolmm(const unsigned long long* __restrict__ srcbits,
                         const unsigned long long* __restrict__ mat,
                         unsigned long long* __restrict__ out) {
    const int wave = threadIdx.x >> 6;
    const int lane = threadIdx.x & 63;
    const int i = blockIdx.x * 4 + wave;
    unsigned long long myword = srcbits[(size_t)i * WPR + lane];
    unsigned long long acc = 0ull;
    for (int w = 0; w < WPR; ++w) {
        unsigned long long bits = __shfl(myword, w, 64);
        while (bits) {
            int b = __builtin_ctzll(bits);
            bits &= bits - 1;
            acc |= mat[(size_t)(w * 64 + b) * WPR + lane];
        }
    }
    out[(size_t)i * WPR + lane] = acc;
}

// ---- hop pass A (all 3 hops): h = softmax_masked(rank1 e) @ W1h, 16 rows/block ----
__global__ __launch_bounds__(1024) void k_hopA(const unsigned long long* __restrict__ B1,
                                               const unsigned long long* __restrict__ B2,
                                               const unsigned long long* __restrict__ B3,
                                               const float* __restrict__ s1v,
                                               const float* __restrict__ s2v,
                                               const float* __restrict__ s2mx,
                                               const unsigned short* __restrict__ W1hTb,
                                               unsigned short* __restrict__ h_rm,
                                               unsigned short* __restrict__ h_cm) {
    __shared__ unsigned short wl[16 * 4096] __attribute__((aligned(16)));  // 128 KB granules
    __shared__ f32x4 pacc[8][64];                                           // 8 KB
    __shared__ float Zi[16];
    const int hop = blockIdx.x >> 8;
    const int i0 = (blockIdx.x & 255) * 16;
    const unsigned long long* Bk = (hop == 0) ? B1 : ((hop == 1) ? B2 : B3);
    unsigned short* hrm = h_rm + (size_t)hop * NN * HH;
    unsigned short* hcm = h_cm + (size_t)hop * NN * HH;
    const int t = threadIdx.x, wv = t >> 6, lane = t & 63;
    // wave wv owns strip row wv; its mask row lives in registers
    const unsigned long long bw = Bk[(size_t)(i0 + wv) * WPR + lane];
    const float s1r = s1v[i0 + wv];
    const float M = lrelu(s1r + s2mx[0]);
    float z = 0.f;
#pragma unroll
    for (int jj = 0; jj < 8; ++jj) {
        const int j0 = lane * 8 + jj * 512;
        const unsigned long long wbits = __shfl(bw, (lane >> 3) + jj * 8, 64);
        const unsigned int mb = (unsigned int)(wbits >> ((lane & 7) * 8)) & 0xFFu;
        const float4 va = *reinterpret_cast<const float4*>(&s2v[j0]);
        const float4 vb = *reinterpret_cast<const float4*>(&s2v[j0 + 4]);
        float sv[8] = {va.x, va.y, va.z, va.w, vb.x, vb.y, vb.z, vb.w};
        bf16x8 pk;
#pragma unroll
        for (int b = 0; b < 8; ++b) {
            float f = ((mb >> b) & 1u) ? __expf(lrelu(s1r + sv[b]) - M) : 0.f;
            z += f;
            pk[b] = (short)f2bf(f);
        }
        *reinterpret_cast<bf16x8*>(&wl[agran((lane >> 2) + jj * 16, ((lane & 3) << 4) | wv)]) = pk;
    }
#pragma unroll
    for (int m = 1; m < 64; m <<= 1) z += __shfl_xor(z, m, 64);
    if (lane == 0) Zi[wv] = 1.f / z;
    __syncthreads();
    // GEMM split-K: 8 col-waves x 2 K-halves; A-reads conflict-free granules
    const int kh = wv >> 3, kbase = kh * 2048;
    const int col = ((wv & 7) << 4) + (lane & 15);
    const int kg = lane >> 4;
    f32x4 acc = {0.f, 0.f, 0.f, 0.f};
    const unsigned short* bp = W1hTb + (size_t)col * NN + kg * 8 + kbase;
#pragma unroll 4
    for (int k0 = 0; k0 < 2048; k0 += 32) {
        const int c = (kbase + k0) >> 5;
        bf16x8 a = *reinterpret_cast<const bf16x8*>(&wl[agran(c, lane)]);
        bf16x8 b = *reinterpret_cast<const bf16x8*>(&bp[k0]);
        acc = __builtin_amdgcn_mfma_f32_16x16x32_bf16(a, b, acc, 0, 0, 0);
    }
    if (kh == 1) pacc[wv & 7][lane] = acc;
    __syncthreads();
    if (kh == 0) {
        f32x4 p = pacc[wv][lane];
#pragma unroll
        for (int ri = 0; ri < 4; ++ri) {
            const int row = kg * 4 + ri;
            const unsigned short hv = f2bf((acc[ri] + p[ri]) * Zi[row]);
            hrm[(size_t)(i0 + row) * HH + col] = hv;
            hcm[(size_t)col * NN + i0 + row] = hv;
        }
    }
}

// ---- hop pass B (all 3 hops): S=h@W2h^T, masked softmax, acc = w @ h ----
__global__ __launch_bounds__(1024) void k_hopB(const unsigned long long* __restrict__ B1,
                                               const unsigned long long* __restrict__ B2,
                                               const unsigned long long* __restrict__ B3,
                                               const unsigned short* __restrict__ h_rm,
                                               const unsigned short* __restrict__ W2hb,
                                               const unsigned short* __restrict__ h_cm,
                                               unsigned short* __restrict__ accb) {
    __shared__ unsigned short sl[16 * 4096] __attribute__((aligned(16)));  // 128 KB
    __shared__ f32x4 pacc[8][64];                                           // 8 KB
    __shared__ float redM[16][16];
    __shared__ float Zi[16];
    const int hop = blockIdx.x >> 8;
    const int i0 = (blockIdx.x & 255) * 16;
    const unsigned long long* Bk = (hop == 0) ? B1 : ((hop == 1) ? B2 : B3);
    const unsigned short* hrm = h_rm + (size_t)hop * NN * HH;
    const unsigned short* hcm = h_cm + (size_t)hop * NN * HH;
    unsigned short* ab = accb + (size_t)hop * NN * HH;
    const int t = threadIdx.x, wv = t >> 6, lane = t & 63;
    const int kg = lane >> 4, arow = lane & 15;
    const unsigned long long bw = Bk[(size_t)(i0 + wv) * WPR + lane];
    // A fragments: strip rows of h (K=128 -> 4 frags)
    bf16x8 af[4];
#pragma unroll
    for (int ks = 0; ks < 4; ++ks)
        af[ks] = *reinterpret_cast<const bf16x8*>(&hrm[(size_t)(i0 + arow) * HH + ks * 32 + kg * 8]);
    // S sweep: 16 waves x 16 col-tiles; S bf16 -> row-major swizzled; max in regs
    float vmax[4] = {-3e38f, -3e38f, -3e38f, -3e38f};
    for (int m = 0; m < 16; ++m) {
        const int col = ((wv * 16 + m) << 4) + arow;
        f32x4 acc = {0.f, 0.f, 0.f, 0.f};
#pragma unroll
        for (int ks = 0; ks < 4; ++ks) {
            bf16x8 b = *reinterpret_cast<const bf16x8*>(&W2hb[(size_t)col * HH + ks * 32 + kg * 8]);
            acc = __builtin_amdgcn_mfma_f32_16x16x32_bf16(af[ks], b, acc, 0, 0, 0);
        }
#pragma unroll
        for (int ri = 0; ri < 4; ++ri) {
            const int row = kg * 4 + ri;
            sl[row * 4096 + (col ^ ((row & 7) << 3))] = f2bf(acc[ri]);
            vmax[ri] = fmaxf(vmax[ri], acc[ri]);
        }
    }
#pragma unroll
    for (int ri = 0; ri < 4; ++ri) {
        vmax[ri] = fmaxf(vmax[ri], __shfl_xor(vmax[ri], 1, 64));
        vmax[ri] = fmaxf(vmax[ri], __shfl_xor(vmax[ri], 2, 64));
        vmax[ri] = fmaxf(vmax[ri], __shfl_xor(vmax[ri], 4, 64));
        vmax[ri] = fmaxf(vmax[ri], __shfl_xor(vmax[ri], 8, 64));
    }
    if (arow == 0) {
#pragma unroll
        for (int ri = 0; ri < 4; ++ri) redM[wv][kg * 4 + ri] = vmax[ri];
    }
    __syncthreads();
    // read own row back to regs (contiguous, conflict-free)
    float Mx = -3e38f;
#pragma unroll
    for (int w = 0; w < 16; ++w) Mx = fmaxf(Mx, redM[w][wv]);
    const int rsw = (wv & 7) << 3;
    bf16x8 sreg[8];
#pragma unroll
    for (int jj = 0; jj < 8; ++jj)
        sreg[jj] = *reinterpret_cast<const bf16x8*>(&sl[wv * 4096 + ((lane * 8 + jj * 512) ^ rsw)]);
    __syncthreads();
    // masked exp in regs -> write A-fragment granules in place
    float z = 0.f;
#pragma unroll
    for (int jj = 0; jj < 8; ++jj) {
        const unsigned long long wbits = __shfl(bw, (lane >> 3) + jj * 8, 64);
        const unsigned int mb = (unsigned int)(wbits >> ((lane & 7) * 8)) & 0xFFu;
        bf16x8 pk;
#pragma unroll
        for (int b = 0; b < 8; ++b) {
            float f = ((mb >> b) & 1u) ? __expf(bf2f((unsigned short)sreg[jj][b]) - Mx) : 0.f;
            z += f;
            pk[b] = (short)f2bf(f);
        }
        *reinterpret_cast<bf16x8*>(&sl[agran((lane >> 2) + jj * 16, ((lane & 3) << 4) | wv)]) = pk;
    }
#pragma unroll
    for (int m = 1; m < 64; m <<= 1) z += __shfl_xor(z, m, 64);
    if (lane == 0) Zi[wv] = 1.f / z;
    __syncthreads();
    // GEMM2 split-K: acc strip = (w/Z) @ h
    const int kh = wv >> 3, kbase = kh * 2048;
    const int col = ((wv & 7) << 4) + (lane & 15);
    f32x4 acc = {0.f, 0.f, 0.f, 0.f};
    const unsigned short* bp = hcm + (size_t)col * NN + kg * 8 + kbase;
#pragma unroll 4
    for (int k0 = 0; k0 < 2048; k0 += 32) {
        const int c = (kbase + k0) >> 5;
        bf16x8 a = *reinterpret_cast<const bf16x8*>(&sl[agran(c, lane)]);
        bf16x8 b = *reinterpret_cast<const bf16x8*>(&bp[k0]);
        acc = __builtin_amdgcn_mfma_f32_16x16x32_bf16(a, b, acc, 0, 0, 0);
    }
    if (kh == 1) pacc[wv & 7][lane] = acc;
    __syncthreads();
    if (kh == 0) {
        f32x4 p = pacc[wv][lane];
#pragma unroll
        for (int ri = 0; ri < 4; ++ri) {
            const int row = kg * 4 + ri;
            ab[(size_t)(i0 + row) * HH + col] = f2bf((acc[ri] + p[ri]) * Zi[row]);
        }
    }
}

// ---- finalize: out = [U_l + sum(acc_k) ; sum(acc_k)] ----
__global__ void k_fin(const float* __restrict__ Ul, const unsigned short* __restrict__ accb,
                      float* __restrict__ out) {
    int idx = blockIdx.x * 256 + threadIdx.x;
    float a = bf2f(accb[idx]) + bf2f(accb[NN * HH + idx]) + bf2f(accb[2 * NN * HH + idx]);
    out[idx] = Ul[idx] + a;
    out[NN * HH + idx] = a;
}

extern "C" void kernel_launch(void* const* d_in, const int* in_sizes, int n_in,
                              void* d_out, int out_size, void* d_ws, size_t ws_size,
                              hipStream_t stream) {
    const float* X   = (const float*)d_in[0];
    const float* A   = (const float*)d_in[1];
    const float* Ul  = (const float*)d_in[2];
    const float* W1w = (const float*)d_in[3];
    const float* W2w = (const float*)d_in[4];
    const float* r   = (const float*)d_in[5];
    float* out = (float*)d_out;

    char* ws = (char*)d_ws;
    // 0-2MB: W1h f32 (dead after hopA) overlapped by accb bf16 3MB @0-3 (hopB phase;
    //        also overlaps s1/s2/s2mx @2-3MB, dead after hopA). Total footprint 17MB.
    float* W1h            = (float*)(ws + (0ull << 20));
    unsigned short* accb  = (unsigned short*)(ws + (0ull << 20));       // 3 MB bf16 x3 hops
    float* s1             = (float*)(ws + (2ull << 20));                // 16 KB
    float* s2             = (float*)(ws + (2ull << 20) + (64 << 10));   // 16 KB
    float* s2mx           = (float*)(ws + (2ull << 20) + (128 << 10));  // 4 B
    unsigned short* W1hTb = (unsigned short*)(ws + (3ull << 20));       // 1 MB (128x4096)
    unsigned short* W2hb  = (unsigned short*)(ws + (4ull << 20));       // 1 MB (4096x128)
    unsigned short* h_rm  = (unsigned short*)(ws + (5ull << 20));       // 3 MB x3 hops
    unsigned short* h_cm  = (unsigned short*)(ws + (8ull << 20));       // 3 MB x3 hops
    unsigned long long* B1 = (unsigned long long*)(ws + (11ull << 20)); // 2 MB
    unsigned long long* B2 = (unsigned long long*)(ws + (13ull << 20)); // 2 MB
    unsigned long long* B3 = (unsigned long long*)(ws + (15ull << 20)); // 2 MB

    k_xw<<<NN / 16, 256, 0, stream>>>(X, W1w, W2w, W1h, W1hTb, W2hb);
    k_s<<<NN / 256, 256, 0, stream>>>(W1h, r, s1, s2);
    k_gmax<<<1, 256, 0, stream>>>(s2, s2mx);
    k_b1<<<NN / 4, 256, 0, stream>>>(A, B1);
    k_boolmm<<<NN / 4, 256, 0, stream>>>(B1, B1, B2);
    k_boolmm<<<NN / 4, 256, 0, stream>>>(B1, B2, B3);

    k_hopA<<<3 * (NN / 16), 1024, 0, stream>>>(B1, B2, B3, s1, s2, s2mx, W1hTb, h_rm, h_cm);
    k_hopB<<<3 * (NN / 16), 1024, 0, stream>>>(B1, B2, B3, h_rm, W2hb, h_cm, accb);
    k_fin<<<NN * HH / 256, 256, 0, stream>>>(Ul, accb, out);
}

// Round 5
// 293.152 us; speedup vs baseline: 9.7941x; 1.3242x over previous
//
#include <hip/hip_runtime.h>
#include <hip/hip_bf16.h>

// LSDAN: 3-hop masked graph attention, N=4096, IN_F=256, H=128.
//  - masks of A^k via boolean bitset reachability (A is 0/1 with self-loops).
//  - e is rank-1: e[i][j]=lrelu(s1[i]+s2[j]); shift M = lrelu(s1+gmax(s2)) (valid upper bound).
//  - hopA: single-pass "flash": P tiles straight from rank-1 e, PV-MFMA, fixed M.
//  - hopB: online-softmax flash: S tile in f32 regs (MFMA), running max/rescale,
//    P granules in LDS, PV-MFMA. S is never materialized (no 128KB buffer).
//  - All MFMA B-operands staged in a 32KB LDS tile (XOR-swizzled, conflict-free),
//    loads issued early / ds_writes late so HBM/L2 latency hides under compute.
//  - 59-64KB LDS/block -> 2 blocks/CU; 384 blocks all co-resident.

#define NN 4096
#define INF 256
#define HH 128
#define WPR 64
#define ALPHA_S 0.2f

typedef short bf16x8 __attribute__((ext_vector_type(8)));
typedef float f32x4 __attribute__((ext_vector_type(4)));

__device__ __forceinline__ float lrelu(float x) { return x > 0.f ? x : ALPHA_S * x; }
__device__ __forceinline__ unsigned short f2bf(float x) {
    __hip_bfloat16 h = __float2bfloat16(x);
    return *reinterpret_cast<unsigned short*>(&h);
}
__device__ __forceinline__ float bf2f(unsigned short u) {
    return __uint_as_float(((unsigned int)u) << 16);
}

// ---- W1h = X@W1^T (f32 + bf16-transposed), W2h = X@W2^T (bf16 row-major) ----
__global__ __launch_bounds__(256) void k_xw(const float* __restrict__ X,
                                            const float* __restrict__ W1,
                                            const float* __restrict__ W2,
                                            float* __restrict__ W1h,
                                            unsigned short* __restrict__ W1hTb,
                                            unsigned short* __restrict__ W2hb) {
    __shared__ float xs[16 * INF];
    const int row0 = blockIdx.x * 16;
    const int t = threadIdx.x;
    for (int v = t; v < 16 * INF; v += 256) xs[v] = X[(size_t)row0 * INF + v];
    __syncthreads();
    const int c = t;
    const float* W = (c < HH) ? (W1 + (size_t)c * INF) : (W2 + (size_t)(c - HH) * INF);
    float acc[16];
#pragma unroll
    for (int r = 0; r < 16; ++r) acc[r] = 0.f;
    for (int k = 0; k < INF; ++k) {
        float wv = W[k];
#pragma unroll
        for (int r = 0; r < 16; ++r) acc[r] += xs[r * INF + k] * wv;
    }
    if (c < HH) {
        for (int r = 0; r < 16; ++r) {
            W1h[(size_t)(row0 + r) * HH + c] = acc[r];
            W1hTb[(size_t)c * NN + row0 + r] = f2bf(acc[r]);
        }
    } else {
        const int cc = c - HH;
        for (int r = 0; r < 16; ++r) W2hb[(size_t)(row0 + r) * HH + cc] = f2bf(acc[r]);
    }
}

// ---- s1 = W1h @ r[:H], s2 = W1h @ r[H:] ----
__global__ void k_s(const float* __restrict__ W1h, const float* __restrict__ r,
                    float* __restrict__ s1, float* __restrict__ s2) {
    int i = blockIdx.x * blockDim.x + threadIdx.x;
    if (i >= NN) return;
    float a = 0.f, b = 0.f;
    for (int h = 0; h < HH; ++h) {
        float v = W1h[(size_t)i * HH + h];
        a += v * r[h];
        b += v * r[HH + h];
    }
    s1[i] = a;
    s2[i] = b;
}

// ---- global max of s2 ----
__global__ void k_gmax(const float* __restrict__ s2, float* __restrict__ out) {
    __shared__ float red[256];
    const int t = threadIdx.x;
    float m = -3e38f;
    for (int i = t; i < NN; i += 256) m = fmaxf(m, s2[i]);
    red[t] = m;
    __syncthreads();
    for (int off = 128; off; off >>= 1) {
        if (t < off) red[t] = fmaxf(red[t], red[t + off]);
        __syncthreads();
    }
    if (t == 0) out[0] = red[0];
}

// ---- B1[i] bitset from A row i ----
__global__ void k_b1(const float* __restrict__ A, unsigned long long* __restrict__ B1) {
    const int wave = threadIdx.x >> 6;
    const int lane = threadIdx.x & 63;
    const int i = blockIdx.x * 4 + wave;
    for (int w = 0; w < WPR; ++w) {
        float a = A[(size_t)i * NN + w * 64 + lane];
        unsigned long long m = __ballot(a != 0.0f);
        if (lane == 0) B1[(size_t)i * WPR + w] = m;
    }
}

// ---- boolean matmul for reachability ----
__global__ void k_boolmm(const unsigned long long* __restrict__ srcbits,
                         const unsigned long long* __restrict__ mat,
                         unsigned long long* __restrict__ out) {
    const int wave = threadIdx.x >> 6;
    const int lane = threadIdx.x & 63;
    const int i = blockIdx.x * 4 + wave;
    unsigned long long myword = srcbits[(size_t)i * WPR + lane];
    unsigned long long acc = 0ull;
    for (int w = 0; w < WPR; ++w) {
        unsigned long long bits = __shfl(myword, w, 64);
        while (bits) {
            int b = __builtin_ctzll(bits);
            bits &= bits - 1;
            acc |= mat[(size_t)(w * 64 + b) * WPR + lane];
        }
    }
    out[(size_t)i * WPR + lane] = acc;
}

// P-granule address (u16 index): sub-tile s (rows 16s..), K-chunk cc (32 cols),
// lane-id lp = (kg<<4)|arow. Read side: lane reads ((s<<8)+(cc<<6)+(lane^cc))<<3.
__device__ __forceinline__ int pgran(int s, int cc, int lp) {
    return ((s << 8) + (cc << 6) + (lp ^ cc)) << 3;
}

// ---- hop pass A (flash, 32 rows/block): h = softmax_masked(rank1 e) @ W1h ----
__global__ __launch_bounds__(512, 4) void k_hopA(const unsigned long long* __restrict__ B1,
                                                 const unsigned long long* __restrict__ B2,
                                                 const unsigned long long* __restrict__ B3,
                                                 const float* __restrict__ s1v,
                                                 const float* __restrict__ s2v,
                                                 const float* __restrict__ s2mx,
                                                 const unsigned short* __restrict__ W1hTb,
                                                 unsigned short* __restrict__ h_rm,
                                                 unsigned short* __restrict__ h_cm) {
    __shared__ unsigned short stg[128 * 128] __attribute__((aligned(16)));  // 32 KB B tile
    __shared__ unsigned short Pb[4096] __attribute__((aligned(16)));        // 8 KB P granules
    __shared__ unsigned long long bits[32][WPR];                            // 16 KB
    __shared__ unsigned short outl[32 * 128] __attribute__((aligned(16)));  // 8 KB
    __shared__ float Zl[32];
    const int bid = blockIdx.x;
    const int hop = bid >> 7;
    const int i0 = (bid & 127) * 32;
    const unsigned long long* Bk = (hop == 0) ? B1 : ((hop == 1) ? B2 : B3);
    unsigned short* hrm = h_rm + (size_t)hop * NN * HH;
    unsigned short* hcm = h_cm + (size_t)hop * NN * HH;
    const int t = threadIdx.x, w = t >> 6, lane = t & 63;
    for (int v = t; v < 32 * WPR; v += 512)
        bits[v >> 6][v & 63] = Bk[(size_t)(i0 + (v >> 6)) * WPR + (v & 63)];
    if (t < 32) Zl[t] = 0.f;
    // P phase mapping: wave w owns rows 4w..4w+3; lane -> row 4w+(lane>>4), cols (lane&15)*8
    const int prow = 4 * w + (lane >> 4);
    const float s1r = s1v[i0 + prow];
    const float M = lrelu(s1r + s2mx[0]);
    // PV mapping: wave w -> (wr=w>>2, wc=w&3); rows 16wr.., dims 32wc..
    const int wr = w >> 2, wc = w & 3;
    const int kg = lane >> 4, ar = lane & 15;
    f32x4 o0 = {0.f, 0.f, 0.f, 0.f}, o1 = {0.f, 0.f, 0.f, 0.f};
    // preload B tile 0 into regs
    bf16x8 sreg[4];
#pragma unroll
    for (int it = 0; it < 4; ++it) {
        int p = (it * 512 + t) * 8;
        sreg[it] = *reinterpret_cast<const bf16x8*>(&W1hTb[(size_t)(p >> 7) * NN + (p & 127)]);
    }
    for (int ct = 0; ct < 32; ++ct) {
        const int c0 = ct * 128;
        // write staged tile (XOR-swizzled)
#pragma unroll
        for (int it = 0; it < 4; ++it) {
            int p = (it * 512 + t) * 8;
            int d = p >> 7, c = p & 127;
            *reinterpret_cast<bf16x8*>(&stg[d * 128 + (c ^ ((d & 7) << 3))]) = sreg[it];
        }
        __syncthreads();  // B1: stg ready, Pb free (prev B3)
        // P phase: masked exp of rank-1 e, straight to granules
        {
            const int cb = ar * 8;
            const unsigned int mb =
                (unsigned int)(bits[prow][(c0 + cb) >> 6] >> ((c0 + cb) & 63)) & 0xFFu;
            const float4 va = *reinterpret_cast<const float4*>(&s2v[c0 + cb]);
            const float4 vb = *reinterpret_cast<const float4*>(&s2v[c0 + cb + 4]);
            float sv[8] = {va.x, va.y, va.z, va.w, vb.x, vb.y, vb.z, vb.w};
            bf16x8 pk;
            float z = 0.f;
#pragma unroll
            for (int b = 0; b < 8; ++b) {
                float f = ((mb >> b) & 1u) ? __expf(lrelu(s1r + sv[b]) - M) : 0.f;
                z += f;
                pk[b] = (short)f2bf(f);
            }
            const int cc = ar >> 2;
            const int lp = ((lane & 3) << 4) | (prow & 15);
            *reinterpret_cast<bf16x8*>(&Pb[pgran(w >> 2, cc, lp)]) = pk;
#pragma unroll
            for (int m = 1; m < 16; m <<= 1) z += __shfl_xor(z, m, 64);
            if (ar == 0) Zl[prow] += z;
        }
        // prefetch next B tile during PV
        if (ct < 31) {
#pragma unroll
            for (int it = 0; it < 4; ++it) {
                int p = (it * 512 + t) * 8;
                sreg[it] = *reinterpret_cast<const bf16x8*>(
                    &W1hTb[(size_t)(p >> 7) * NN + c0 + 128 + (p & 127)]);
            }
        }
        __syncthreads();  // B2: Pb ready
        // PV: o += P @ W1hT_tile
        const int d0 = 32 * wc + ar, d1 = d0 + 16;
#pragma unroll
        for (int cc = 0; cc < 4; ++cc) {
            bf16x8 a = *reinterpret_cast<const bf16x8*>(&Pb[pgran(wr, cc, lane ^ cc)] - 0) ;
            a = *reinterpret_cast<const bf16x8*>(&Pb[((wr << 8) + (cc << 6) + (lane ^ cc)) << 3]);
            const int kk = cc * 32 + kg * 8;
            bf16x8 b0 = *reinterpret_cast<const bf16x8*>(&stg[d0 * 128 + (kk ^ ((d0 & 7) << 3))]);
            bf16x8 b1 = *reinterpret_cast<const bf16x8*>(&stg[d1 * 128 + (kk ^ ((d1 & 7) << 3))]);
            o0 = __builtin_amdgcn_mfma_f32_16x16x32_bf16(a, b0, o0, 0, 0, 0);
            o1 = __builtin_amdgcn_mfma_f32_16x16x32_bf16(a, b1, o1, 0, 0, 0);
        }
        __syncthreads();  // B3: stg/Pb free
    }
    // normalize + stage output in LDS
#pragma unroll
    for (int ri = 0; ri < 4; ++ri) {
        const int row = 16 * wr + 4 * kg + ri;
        const float iz = 1.f / Zl[row];
        outl[row * 128 + 32 * wc + ar] = f2bf(o0[ri] * iz);
        outl[row * 128 + 32 * wc + 16 + ar] = f2bf(o1[ri] * iz);
    }
    __syncthreads();
    // coalesced h_rm write: thread t -> row t>>4, 8 dims
    {
        const int row = t >> 4, dd = (t & 15) * 8;
        bf16x8 v = *reinterpret_cast<const bf16x8*>(&outl[row * 128 + dd]);
        *reinterpret_cast<bf16x8*>(&hrm[(size_t)(i0 + row) * HH + dd]) = v;
    }
    // coalesced h_cm write: thread t -> dim t>>2, rows 8*(t&3)..
    {
        const int d = t >> 2, r0 = (t & 3) * 8;
        bf16x8 v;
#pragma unroll
        for (int j = 0; j < 8; ++j) v[j] = (short)outl[(r0 + j) * 128 + d];
        *reinterpret_cast<bf16x8*>(&hcm[(size_t)d * NN + i0 + r0]) = v;
    }
}

// ---- hop pass B (flash, 32 rows/block): S=h@W2h^T, online softmax, O = P@h ----
__global__ __launch_bounds__(512, 4) void k_hopB(const unsigned long long* __restrict__ B1,
                                                 const unsigned long long* __restrict__ B2,
                                                 const unsigned long long* __restrict__ B3,
                                                 const unsigned short* __restrict__ h_rm,
                                                 const unsigned short* __restrict__ W2hb,
                                                 const unsigned short* __restrict__ h_cm,
                                                 unsigned short* __restrict__ accb) {
    __shared__ unsigned short stg[128 * 128] __attribute__((aligned(16)));  // 32 KB
    __shared__ unsigned short Pb[4096] __attribute__((aligned(16)));        // 8 KB
    __shared__ unsigned long long bits[32][WPR];                            // 16 KB
    __shared__ float redM[4][32];
    __shared__ float redZ[4][32];
    __shared__ float mZ[2][32];
    __shared__ float fac[32];
    __shared__ float zZ[32];
    const int bid = blockIdx.x;
    const int hop = bid >> 7;
    const int i0 = (bid & 127) * 32;
    const unsigned long long* Bk = (hop == 0) ? B1 : ((hop == 1) ? B2 : B3);
    const unsigned short* hrm = h_rm + (size_t)hop * NN * HH;
    const unsigned short* hcm = h_cm + (size_t)hop * NN * HH;
    unsigned short* ab = accb + (size_t)hop * NN * HH;
    const int t = threadIdx.x, w = t >> 6, lane = t & 63;
    const int wr = w >> 2, wc = w & 3;
    const int kg = lane >> 4, ar = lane & 15;
    for (int v = t; v < 32 * WPR; v += 512)
        bits[v >> 6][v & 63] = Bk[(size_t)(i0 + (v >> 6)) * WPR + (v & 63)];
    if (t < 32) { mZ[0][t] = -3e38f; zZ[t] = 0.f; }
    // A fragments for S: rows 16wr+ar of the h strip, K=128
    bf16x8 af[4];
#pragma unroll
    for (int ks = 0; ks < 4; ++ks)
        af[ks] = *reinterpret_cast<const bf16x8*>(
            &hrm[(size_t)(i0 + 16 * wr + ar) * HH + ks * 32 + kg * 8]);
    f32x4 o0 = {0.f, 0.f, 0.f, 0.f}, o1 = {0.f, 0.f, 0.f, 0.f};
    // preload W2 tile 0
    bf16x8 sreg[4];
#pragma unroll
    for (int it = 0; it < 4; ++it) {
        int p = (it * 512 + t) * 8;
        sreg[it] = *reinterpret_cast<const bf16x8*>(&W2hb[(size_t)(p >> 7) * HH + (p & 127)]);
    }
    for (int ct = 0; ct < 32; ++ct) {
        const int c0 = ct * 128;
        const int pp = ct & 1;
        // write W2 tile (swizzled: [col][k])
#pragma unroll
        for (int it = 0; it < 4; ++it) {
            int p = (it * 512 + t) * 8;
            int col = p >> 7, k = p & 127;
            *reinterpret_cast<bf16x8*>(&stg[col * 128 + (k ^ ((col & 7) << 3))]) = sreg[it];
        }
        __syncthreads();  // B1: W2 tile ready
        // S tile: rows 16wr.., cols 32wc + {ar, ar+16}
        f32x4 s0 = {0.f, 0.f, 0.f, 0.f}, s1 = {0.f, 0.f, 0.f, 0.f};
        const int cA = 32 * wc + ar, cB = cA + 16;
#pragma unroll
        for (int ks = 0; ks < 4; ++ks) {
            const int kk = ks * 32 + kg * 8;
            bf16x8 b0 = *reinterpret_cast<const bf16x8*>(&stg[cA * 128 + (kk ^ ((cA & 7) << 3))]);
            bf16x8 b1 = *reinterpret_cast<const bf16x8*>(&stg[cB * 128 + (kk ^ ((cB & 7) << 3))]);
            s0 = __builtin_amdgcn_mfma_f32_16x16x32_bf16(af[ks], b0, s0, 0, 0, 0);
            s1 = __builtin_amdgcn_mfma_f32_16x16x32_bf16(af[ks], b1, s1, 0, 0, 0);
        }
        // per-row max over this wave's 32 cols
        f32x4 mx;
#pragma unroll
        for (int ri = 0; ri < 4; ++ri) mx[ri] = fmaxf(s0[ri], s1[ri]);
#pragma unroll
        for (int ri = 0; ri < 4; ++ri) {
            mx[ri] = fmaxf(mx[ri], __shfl_xor(mx[ri], 1, 64));
            mx[ri] = fmaxf(mx[ri], __shfl_xor(mx[ri], 2, 64));
            mx[ri] = fmaxf(mx[ri], __shfl_xor(mx[ri], 4, 64));
            mx[ri] = fmaxf(mx[ri], __shfl_xor(mx[ri], 8, 64));
        }
        if (ar == 0) {
#pragma unroll
            for (int ri = 0; ri < 4; ++ri) redM[wc][16 * wr + 4 * kg + ri] = mx[ri];
        }
        __syncthreads();  // B2: redM ready; W2 tile consumed
        // combined running max (each lane for its 4 rows; t<32 updates state)
        float Mn[4];
#pragma unroll
        for (int ri = 0; ri < 4; ++ri) {
            const int row = 16 * wr + 4 * kg + ri;
            float m = fmaxf(fmaxf(redM[0][row], redM[1][row]), fmaxf(redM[2][row], redM[3][row]));
            Mn[ri] = fmaxf(m, mZ[pp][row]);
        }
        if (t < 32) {
            float mo = mZ[pp][t];
            float m = fmaxf(fmaxf(redM[0][t], redM[1][t]), fmaxf(redM[2][t], redM[3][t]));
            m = fmaxf(m, mo);
            mZ[pp ^ 1][t] = m;
            fac[t] = __expf(mo - m);
        }
        // prefetch hT tile into regs (latency hides under exp phase)
        bf16x8 hreg[4];
#pragma unroll
        for (int it = 0; it < 4; ++it) {
            int p = (it * 512 + t) * 8;
            hreg[it] = *reinterpret_cast<const bf16x8*>(
                &h_cm[(size_t)hop * NN * HH + (size_t)(p >> 7) * NN + c0 + (p & 127)]);
        }
        // masked exp -> P granules; per-row partial sums
        {
            const int woff = (c0 >> 6);
            const int w0 = woff + ((32 * wc) >> 6);
            const int w1 = woff + ((32 * wc + 16) >> 6);
            const int b0p = (32 * wc + ar) & 63;
            const int b1p = (32 * wc + 16 + ar) & 63;
            f32x4 zp;
#pragma unroll
            for (int ri = 0; ri < 4; ++ri) {
                const int row = 16 * wr + 4 * kg + ri;
                const unsigned int m0 = (unsigned int)(bits[row][w0] >> b0p) & 1u;
                const unsigned int m1 = (unsigned int)(bits[row][w1] >> b1p) & 1u;
                float e0 = m0 ? __expf(s0[ri] - Mn[ri]) : 0.f;
                float e1 = m1 ? __expf(s1[ri] - Mn[ri]) : 0.f;
                zp[ri] = e0 + e1;
                const int arow = 4 * kg + ri;
                const int lp0 = ((0 + (ar >> 3)) << 4) | arow;       // n=0: kg'=(ar>>3)
                const int lp1 = ((2 + (ar >> 3)) << 4) | arow;       // n=1: kg'=2+(ar>>3)
                Pb[(((wr << 8) + (wc << 6) + (lp0 ^ wc)) << 3) + (ar & 7)] = f2bf(e0);
                Pb[(((wr << 8) + (wc << 6) + (lp1 ^ wc)) << 3) + (ar & 7)] = f2bf(e1);
            }
#pragma unroll
            for (int ri = 0; ri < 4; ++ri) {
                zp[ri] += __shfl_xor(zp[ri], 1, 64);
                zp[ri] += __shfl_xor(zp[ri], 2, 64);
                zp[ri] += __shfl_xor(zp[ri], 4, 64);
                zp[ri] += __shfl_xor(zp[ri], 8, 64);
            }
            if (ar == 0) {
#pragma unroll
                for (int ri = 0; ri < 4; ++ri) redZ[wc][16 * wr + 4 * kg + ri] = zp[ri];
            }
        }
        // write hT tile (swizzled: [d][c]) over the W2 tile
#pragma unroll
        for (int it = 0; it < 4; ++it) {
            int p = (it * 512 + t) * 8;
            int d = p >> 7, c = p & 127;
            *reinterpret_cast<bf16x8*>(&stg[d * 128 + (c ^ ((d & 7) << 3))]) = hreg[it];
        }
        __syncthreads();  // B3: P, redZ, hT tile ready
        if (t < 32)
            zZ[t] = zZ[t] * fac[t] + redZ[0][t] + redZ[1][t] + redZ[2][t] + redZ[3][t];
        // rescale running O
#pragma unroll
        for (int ri = 0; ri < 4; ++ri) {
            const float f = fac[16 * wr + 4 * kg + ri];
            o0[ri] *= f;
            o1[ri] *= f;
        }
        // prefetch next W2 tile during PV
        if (ct < 31) {
#pragma unroll
            for (int it = 0; it < 4; ++it) {
                int p = (it * 512 + t) * 8;
                sreg[it] = *reinterpret_cast<const bf16x8*>(
                    &W2hb[(size_t)(c0 + 128 + (p >> 7)) * HH + (p & 127)]);
            }
        }
        // PV: O += P @ hT
        const int d0 = 32 * wc + ar, d1 = d0 + 16;
#pragma unroll
        for (int cc = 0; cc < 4; ++cc) {
            bf16x8 a = *reinterpret_cast<const bf16x8*>(
                &Pb[((wr << 8) + (cc << 6) + (lane ^ cc)) << 3]);
            const int kk = cc * 32 + kg * 8;
            bf16x8 b0 = *reinterpret_cast<const bf16x8*>(&stg[d0 * 128 + (kk ^ ((d0 & 7) << 3))]);
            bf16x8 b1 = *reinterpret_cast<const bf16x8*>(&stg[d1 * 128 + (kk ^ ((d1 & 7) << 3))]);
            o0 = __builtin_amdgcn_mfma_f32_16x16x32_bf16(a, b0, o0, 0, 0, 0);
            o1 = __builtin_amdgcn_mfma_f32_16x16x32_bf16(a, b1, o1, 0, 0, 0);
        }
        __syncthreads();  // B4: stg/Pb free for next tile
    }
    // final normalize + write
#pragma unroll
    for (int ri = 0; ri < 4; ++ri) {
        const int row = 16 * wr + 4 * kg + ri;
        const float iz = 1.f / zZ[row];
        const size_t base = (size_t)(i0 + row) * HH;
        ab[base + 32 * wc + ar] = f2bf(o0[ri] * iz);
        ab[base + 32 * wc + 16 + ar] = f2bf(o1[ri] * iz);
    }
}

// ---- finalize: out = [U_l + sum(acc_k) ; sum(acc_k)] ----
__global__ void k_fin(const float* __restrict__ Ul, const unsigned short* __restrict__ accb,
                      float* __restrict__ out) {
    int idx = blockIdx.x * 256 + threadIdx.x;
    float a = bf2f(accb[idx]) + bf2f(accb[NN * HH + idx]) + bf2f(accb[2 * NN * HH + idx]);
    out[idx] = Ul[idx] + a;
    out[NN * HH + idx] = a;
}

extern "C" void kernel_launch(void* const* d_in, const int* in_sizes, int n_in,
                              void* d_out, int out_size, void* d_ws, size_t ws_size,
                              hipStream_t stream) {
    const float* X   = (const float*)d_in[0];
    const float* A   = (const float*)d_in[1];
    const float* Ul  = (const float*)d_in[2];
    const float* W1w = (const float*)d_in[3];
    const float* W2w = (const float*)d_in[4];
    const float* r   = (const float*)d_in[5];
    float* out = (float*)d_out;

    char* ws = (char*)d_ws;
    // accb (hopB phase) overlays W1h + s1/s2/s2mx (dead after hopA). Total 17MB.
    float* W1h            = (float*)(ws + (0ull << 20));
    unsigned short* accb  = (unsigned short*)(ws + (0ull << 20));       // 3 MB bf16 x3 hops
    float* s1             = (float*)(ws + (2ull << 20));                // 16 KB
    float* s2             = (float*)(ws + (2ull << 20) + (64 << 10));   // 16 KB
    float* s2mx           = (float*)(ws + (2ull << 20) + (128 << 10));  // 4 B
    unsigned short* W1hTb = (unsigned short*)(ws + (3ull << 20));       // 1 MB (128x4096)
    unsigned short* W2hb  = (unsigned short*)(ws + (4ull << 20));       // 1 MB (4096x128)
    unsigned short* h_rm  = (unsigned short*)(ws + (5ull << 20));       // 3 MB x3 hops
    unsigned short* h_cm  = (unsigned short*)(ws + (8ull << 20));       // 3 MB x3 hops
    unsigned long long* B1 = (unsigned long long*)(ws + (11ull << 20)); // 2 MB
    unsigned long long* B2 = (unsigned long long*)(ws + (13ull << 20)); // 2 MB
    unsigned long long* B3 = (unsigned long long*)(ws + (15ull << 20)); // 2 MB

    k_xw<<<NN / 16, 256, 0, stream>>>(X, W1w, W2w, W1h, W1hTb, W2hb);
    k_s<<<NN / 256, 256, 0, stream>>>(W1h, r, s1, s2);
    k_gmax<<<1, 256, 0, stream>>>(s2, s2mx);
    k_b1<<<NN / 4, 256, 0, stream>>>(A, B1);
    k_boolmm<<<NN / 4, 256, 0, stream>>>(B1, B1, B2);
    k_boolmm<<<NN / 4, 256, 0, stream>>>(B1, B2, B3);

    k_hopA<<<3 * (NN / 32), 512, 0, stream>>>(B1, B2, B3, s1, s2, s2mx, W1hTb, h_rm, h_cm);
    k_hopB<<<3 * (NN / 32), 512, 0, stream>>>(B1, B2, B3, h_rm, W2hb, h_cm, accb);
    k_fin<<<NN * HH / 256, 256, 0, stream>>>(Ul, accb, out);
}